// Round 6
// baseline (474.264 us; speedup 1.0000x reference)
//
#include <hip/hip_runtime.h>
#include <hip/hip_cooperative_groups.h>
#include <stdint.h>

namespace cg = cooperative_groups;

#define NUM_E 50000
#define EMBED_DIM 128
#define HID_DIM 200
#define BATCH 512
#define NN 50
#define HPAD 208
#define KPAD 224
#define NKT 7      // K tiles of 32 for scores GEMM
#define NTT2 3136  // N fragment tiles padded: 3136*16 = 50176 = 196*256
#define NXB 196
#define NTILES 1600        // 8 yb * 200 (xb slots, 196 valid)
#define PACK_UNITS 784
#define BATCH_UNITS 512
#define NUNITS (BATCH_UNITS + PACK_UNITS + 1)
#define USTRIDE 201
#define MAXGRID 768

typedef short s16x8 __attribute__((ext_vector_type(8)));
typedef float f32x4 __attribute__((ext_vector_type(4)));

__device__ inline unsigned short f2bf(float f) {
  union { float f; unsigned u; } v; v.f = f;
  unsigned r = v.u + 0x7FFF + ((v.u >> 16) & 1);
  return (unsigned short)(r >> 16);
}
__device__ inline float bf2f(unsigned short b) {
  union { unsigned u; float f; } v; v.u = ((unsigned)b) << 16;
  return v.f;
}

__device__ __forceinline__ void gl_lds16(const unsigned short* g, unsigned short* l) {
  __builtin_amdgcn_global_load_lds(
      (const __attribute__((address_space(1))) unsigned int*)g,
      (__attribute__((address_space(3))) unsigned int*)l, 16, 0, 0);
}

// ---------------------------------------------------------------------------
// scores-GEMM tile (64M x 256N, K=224), shared by phases 2 and 3.
// buf: [0,16384) = Bs staging; [16384, 17408+) = red / invD+invS.
// ---------------------------------------------------------------------------
template<int PASS>
__device__ __forceinline__ void gemm_tile(
    int yb, int xb, char* buf, int tid,
    const unsigned short* Ap, const unsigned short* Bp, const float* mlp_b,
    const float* D_ws, float* S_ws, float* out)
{
  unsigned short* Bs = (unsigned short*)buf;
  float* red = (float*)(buf + 16384);
  const int w = tid >> 6, lane = tid & 63;
  const int q = lane >> 4, l15 = lane & 15;
  const int mt0 = yb * 4;
  const int m0 = yb * 64;
  const int ntb = xb * 16 + w * 4;

  __syncthreads();   // protect red/Bs from previous tile's epilogue readers
  if (PASS == 1 && tid < 64) {
    red[tid]      = 0.5f / D_ws[m0 + tid];
    red[64 + tid] = 0.5f / S_ws[m0 + tid];
  }
  float bias[4];
  #pragma unroll
  for (int nl = 0; nl < 4; ++nl) {
    const int col = (ntb + nl) * 16 + l15;
    bias[nl] = (col < NUM_E) ? mlp_b[col] : 0.f;
  }
  const unsigned short* apBase = Ap + (size_t)mt0 * NKT * 512;

  f32x4 acc[4][4];
  #pragma unroll
  for (int i = 0; i < 4; i++)
    #pragma unroll
    for (int j = 0; j < 4; j++) acc[i][j] = (f32x4){0, 0, 0, 0};

  for (int kt = 0; kt < NKT; ++kt) {
    #pragma unroll
    for (int nl = 0; nl < 4; ++nl)
      gl_lds16(Bp + ((size_t)(ntb + nl) * NKT + kt) * 512 + lane * 8,
               &Bs[(w * 4 + nl) * 512]);
    s16x8 a[4];
    #pragma unroll
    for (int mi = 0; mi < 4; ++mi)
      a[mi] = *(const s16x8*)&apBase[((mi * NKT + kt) * 64 + lane) * 8];
    __syncthreads();
    s16x8 bfr[4];
    #pragma unroll
    for (int nl = 0; nl < 4; ++nl)
      bfr[nl] = *(const s16x8*)&Bs[((w * 4 + nl) * 64 + lane) * 8];
    #pragma unroll
    for (int nl = 0; nl < 4; ++nl)
      #pragma unroll
      for (int mi = 0; mi < 4; ++mi)
        acc[mi][nl] = __builtin_amdgcn_mfma_f32_16x16x32_bf16(a[mi], bfr[nl], acc[mi][nl], 0, 0, 0);
    __syncthreads();
  }

  if (PASS == 0) {
    float rs[4][4];
    #pragma unroll
    for (int mi = 0; mi < 4; mi++)
      #pragma unroll
      for (int p = 0; p < 4; p++) rs[mi][p] = 0.f;
    #pragma unroll
    for (int mi = 0; mi < 4; ++mi)
      #pragma unroll
      for (int nl = 0; nl < 4; ++nl) {
        const int col = (ntb + nl) * 16 + l15;
        #pragma unroll
        for (int p = 0; p < 4; p++) {
          const float v = acc[mi][nl][p] + bias[nl];
          rs[mi][p] += (col < NUM_E) ? __expf(v) : 0.f;
        }
      }
    #pragma unroll
    for (int m = 1; m < 16; m <<= 1)
      for (int mi = 0; mi < 4; mi++)
        for (int p = 0; p < 4; p++)
          rs[mi][p] += __shfl_xor(rs[mi][p], m, 64);
    if (l15 == 0)
      for (int mi = 0; mi < 4; mi++)
        for (int p = 0; p < 4; p++)
          red[w * 64 + mi * 16 + q * 4 + p] = rs[mi][p];
    __syncthreads();
    if (tid < 64)
      atomicAdd(&S_ws[m0 + tid],
                red[tid] + red[64 + tid] + red[128 + tid] + red[192 + tid]);
  } else {
    #pragma unroll
    for (int mi = 0; mi < 4; ++mi) {
      #pragma unroll
      for (int p = 0; p < 4; p++) {
        const int rl = mi * 16 + q * 4 + p;
        const float invD = red[rl];
        const float invS = red[64 + rl];
        const int row = m0 + rl;
        #pragma unroll
        for (int nl = 0; nl < 4; ++nl) {
          const int col = (ntb + nl) * 16 + l15;
          if (col < NUM_E) {
            const float v = acc[mi][nl][p] + bias[nl];
            out[(size_t)row * NUM_E + col] = __logf(fmaf(__expf(v), invS, invD));
          }
        }
      }
    }
  }
}

// ---------------------------------------------------------------------------
// Cooperative mega-kernel: everything in one launch.
// ---------------------------------------------------------------------------
__global__ __launch_bounds__(256, 3) void k_all(
    const int* __restrict__ idx, const int* __restrict__ times,
    const float* __restrict__ emb, const float* __restrict__ Ws_w,
    const float* __restrict__ Ws_b, const float* __restrict__ mlp_w,
    const float* __restrict__ mlp_b, float* __restrict__ out,
    unsigned short* __restrict__ Bp, unsigned short* __restrict__ Ap,
    float* __restrict__ poses_f, float* __restrict__ expa_ws,
    float* __restrict__ D_ws, float* __restrict__ S_ws)
{
  __shared__ __align__(16) char buf[40320];
  __shared__ float cc[NN], bb[NN], vv[HID_DIM], red4[4], scaleS;
  __shared__ int sidx[NN];
  const int tid = threadIdx.x;
  const int w = tid >> 6, lane = tid & 63;
  const int q = lane >> 4, l15 = lane & 15;
  cg::grid_group grid = cg::this_grid();

  // ============ PHASE 1: batch xgemm+routing | Bp pack | S zero ============
  for (int u = blockIdx.x; u < NUNITS; u += gridDim.x) {
    __syncthreads();   // buf reuse across units
    if (u < BATCH_UNITS) {
      const int b = u;
      if (tid < NN) {
        sidx[tid] = idx[b * NN + tid];
        bb[tid] = 2.0f / (1.0f + (float)times[b * NN + tid]);
      }
      __syncthreads();
      unsigned short* Afr = (unsigned short*)buf;            // 16384 B
      unsigned short* Bfr = (unsigned short*)(buf + 16384);  // 13312 B per kt
      // stage A fragments: 64 rows (>=NN zero) x 128 k, gather from emb
      for (int v = tid; v < 1024; v += 256) {
        const int row = v >> 4, c = v & 15;
        const int kt = c >> 2, qq = c & 3;
        unsigned short tmp[8] __attribute__((aligned(16)));
        if (row < NN) {
          const float* src = emb + (size_t)sidx[row] * EMBED_DIM + c * 8;
          float4 f0 = *(const float4*)src;
          float4 f1 = *(const float4*)(src + 4);
          tmp[0] = f2bf(f0.x); tmp[1] = f2bf(f0.y); tmp[2] = f2bf(f0.z); tmp[3] = f2bf(f0.w);
          tmp[4] = f2bf(f1.x); tmp[5] = f2bf(f1.y); tmp[6] = f2bf(f1.z); tmp[7] = f2bf(f1.w);
        } else {
          for (int j = 0; j < 8; j++) tmp[j] = 0;
        }
        *(uint4*)&Afr[(((row >> 4) * 4 + kt) * 64 + qq * 16 + (row & 15)) * 8] = *(uint4*)tmp;
      }
      f32x4 acc[4][4];
      #pragma unroll
      for (int i = 0; i < 4; i++)
        #pragma unroll
        for (int j = 0; j < 4; j++) acc[i][j] = (f32x4){0, 0, 0, 0};
      __syncthreads();
      for (int kt = 0; kt < 4; ++kt) {
        // stage B kt-slice: 208 n (>=HID zero) x 32 k from Ws_w
        for (int v = tid; v < 832; v += 256) {
          const int n = v >> 2, cq = v & 3;
          unsigned short tmp[8] __attribute__((aligned(16)));
          if (n < HID_DIM) {
            const float* src = Ws_w + (size_t)n * EMBED_DIM + kt * 32 + cq * 8;
            float4 f0 = *(const float4*)src;
            float4 f1 = *(const float4*)(src + 4);
            tmp[0] = f2bf(f0.x); tmp[1] = f2bf(f0.y); tmp[2] = f2bf(f0.z); tmp[3] = f2bf(f0.w);
            tmp[4] = f2bf(f1.x); tmp[5] = f2bf(f1.y); tmp[6] = f2bf(f1.z); tmp[7] = f2bf(f1.w);
          } else {
            for (int j = 0; j < 8; j++) tmp[j] = 0;
          }
          *(uint4*)&Bfr[((n >> 4) * 64 + cq * 16 + (n & 15)) * 8] = *(uint4*)tmp;
        }
        __syncthreads();
        s16x8 a[4];
        #pragma unroll
        for (int mt = 0; mt < 4; ++mt)
          a[mt] = *(const s16x8*)&Afr[((mt * 4 + kt) * 64 + lane) * 8];
        #pragma unroll
        for (int ii = 0; ii < 4; ++ii) {
          const int nt = w + ii * 4;
          if (nt < 13) {
            s16x8 bv = *(const s16x8*)&Bfr[(nt * 64 + lane) * 8];
            #pragma unroll
            for (int mt = 0; mt < 4; ++mt)
              acc[mt][ii] = __builtin_amdgcn_mfma_f32_16x16x32_bf16(a[mt], bv, acc[mt][ii], 0, 0, 0);
          }
        }
        __syncthreads();
      }
      // epilogue: x = acc + Ws_b into u (fp32, overlays frag LDS)
      float* uu = (float*)buf;
      #pragma unroll
      for (int ii = 0; ii < 4; ++ii) {
        const int nt = w + ii * 4;
        if (nt < 13) {
          const int col = nt * 16 + l15;
          if (col < HID_DIM) {
            const float bv = Ws_b[col];
            #pragma unroll
            for (int mt = 0; mt < 4; ++mt)
              #pragma unroll
              for (int p = 0; p < 4; p++) {
                const int row = mt * 16 + q * 4 + p;
                if (row < NN) uu[row * USTRIDE + col] = acc[mt][ii][p] + bv;
              }
          }
        }
      }
      __syncthreads();
      // L2-normalize rows of u (4 threads/row)
      const int un = tid >> 2, uc0 = (tid & 3) * 50;
      if (un < NN) {
        float s = 0.f;
        for (int j = 0; j < 50; j++) {
          const float x = uu[un * USTRIDE + uc0 + j];
          s += x * x;
        }
        s += __shfl_xor(s, 1, 64);
        s += __shfl_xor(s, 2, 64);
        const float inv = 1.0f / fmaxf(sqrtf(s), 1e-12f);
        for (int j = 0; j < 50; j++) uu[un * USTRIDE + uc0 + j] *= inv;
      }
      __syncthreads();
      // dynamic routing, 3 iters
      for (int it = 0; it < 3; ++it) {
        if (tid < 64) {
          float x = (tid < NN) ? bb[tid] : -1e30f;
          float m = x;
          for (int d = 1; d < 64; d <<= 1) m = fmaxf(m, __shfl_xor(m, d, 64));
          float e = (tid < NN) ? __expf(x - m) : 0.f;
          float s = e;
          for (int d = 1; d < 64; d <<= 1) s += __shfl_xor(s, d, 64);
          if (tid < NN) cc[tid] = e * (float)NN / s;
        }
        __syncthreads();
        float sh = 0.f;
        if (tid < HID_DIM)
          for (int n = 0; n < NN; n++) sh += cc[n] * uu[n * USTRIDE + tid];
        float sq2 = (tid < HID_DIM) ? sh * sh : 0.f;
        for (int d = 1; d < 64; d <<= 1) sq2 += __shfl_xor(sq2, d, 64);
        if ((tid & 63) == 0) red4[tid >> 6] = sq2;
        __syncthreads();
        if (tid == 0) {
          const float t2 = red4[0] + red4[1] + red4[2] + red4[3];
          scaleS = t2 / (1.0f + t2) / sqrtf(t2 + 1e-9f);
        }
        __syncthreads();
        if (tid < HID_DIM) vv[tid] = scaleS * sh;
        __syncthreads();
        if (it < 2) {
          float d = 0.f;
          if (un < NN)
            for (int j = 0; j < 50; j++)
              d += uu[un * USTRIDE + uc0 + j] * vv[uc0 + j];
          d += __shfl_xor(d, 1, 64);
          d += __shfl_xor(d, 2, 64);
          if (un < NN && (tid & 3) == 0) bb[un] += d;
          __syncthreads();
        }
      }
      // outputs: Ap fragments, fp32 poses, expa, D_b
      if (tid < KPAD) {
        const float val = (tid < HID_DIM) ? vv[tid] : 0.f;
        const int kt = tid >> 5, rem = tid & 31, qq = rem >> 3, j = rem & 7;
        const int mt = b >> 4, ll = b & 15;
        Ap[(size_t)(((mt * NKT + kt) * 64) + qq * 16 + ll) * 8 + j] = f2bf(val);
      }
      if (tid < HID_DIM) poses_f[b * HID_DIM + tid] = vv[tid];
      if (tid < 64) {
        float a2 = 0.f; int first = 1;
        const int my = (tid < NN) ? sidx[tid] : -1;
        if (tid < NN) {
          for (int n = 0; n < NN; n++)
            if (sidx[n] == my) { a2 += cc[n]; if (n < tid) first = 0; }
          expa_ws[b * NN + tid] = __expf(a2);
        }
        float contrib = (tid < NN && first) ? (__expf(a2) - 1.0f) : 0.f;
        for (int d = 1; d < 64; d <<= 1) contrib += __shfl_xor(contrib, d, 64);
        if (tid == 0) D_ws[b] = (float)NUM_E + contrib;
      }
    } else if (u < BATCH_UNITS + PACK_UNITS) {
      // ---- coalesced pack of 4 n-tiles of mlp_w into Bp ----
      const int pb = u - BATCH_UNITS;
      unsigned short* smem = (unsigned short*)buf;
      const size_t base_f = (size_t)pb * 64 * HID_DIM;
      const float4* src4 = (const float4*)(mlp_w + base_f);
      for (int i = tid; i < 3200; i += 256) {
        float4 f;
        if (base_f + 4 * (size_t)i + 4 <= (size_t)NUM_E * HID_DIM) f = src4[i];
        else f = make_float4(0.f, 0.f, 0.f, 0.f);
        unsigned short t4[4] __attribute__((aligned(8))) = {
          f2bf(f.x), f2bf(f.y), f2bf(f.z), f2bf(f.w)};
        *(uint2*)&smem[i * 4] = *(uint2*)t4;
      }
      __syncthreads();
      const int nt0 = pb * 4;
      unsigned short* dst = Bp + (size_t)nt0 * NKT * 512;
      for (int s2 = 0; s2 < 7; ++s2) {
        const int fi = s2 * 256 + tid;
        const int fr = fi >> 6;
        const int ln = fi & 63;
        const int nt_l = fr / 7, kt = fr - nt_l * 7;
        const int r = nt_l * 16 + (ln & 15);
        const int kb = kt * 32 + (ln >> 4) * 8;
        uint4 val;
        if (kb < HID_DIM) val = *(const uint4*)&smem[r * HID_DIM + kb];
        else val = make_uint4(0, 0, 0, 0);
        *(uint4*)&dst[(size_t)fi * 8] = val;
      }
    } else {
      S_ws[tid] = 0.f;
      S_ws[256 + tid] = 0.f;
    }
  }
  grid.sync();

  // ============ PHASE 2: scores GEMM pass 0 (S_b accumulation) ============
  for (int t = blockIdx.x; t < NTILES; t += gridDim.x) {
    const int yb = t / 200, xb = t - yb * 200;
    if (xb < NXB)
      gemm_tile<0>(yb, xb, buf, tid, Ap, Bp, mlp_b, D_ws, S_ws, out);
  }
  grid.sync();

  // ============ PHASE 3: scores GEMM pass 1 (write out) ============
  for (int t = blockIdx.x; t < NTILES; t += gridDim.x) {
    const int yb = t / 200, xb = t - yb * 200;
    if (xb < NXB)
      gemm_tile<1>(yb, xb, buf, tid, Ap, Bp, mlp_b, D_ws, S_ws, out);
  }
  grid.sync();

  // ============ PHASE 4: history fixup ============
  for (int s = blockIdx.x * 4 + w; s < BATCH * NN; s += gridDim.x * 4) {
    const int b = s / NN;
    const int j = idx[s];
    float dot = 0.f;
    for (int h = lane; h < HID_DIM; h += 64)
      dot += poses_f[b * HID_DIM + h] * mlp_w[(size_t)j * HID_DIM + h];
    for (int m = 1; m < 64; m <<= 1) dot += __shfl_xor(dot, m, 64);
    if (lane == 0) {
      const float sc = dot + mlp_b[j];
      out[(size_t)b * NUM_E + j] = __logf(0.5f * expa_ws[s] / D_ws[b] +
                                          0.5f * __expf(sc) / S_ws[b]);
    }
  }
}

// ===========================================================================
// Fallback pipeline (r5, proven) in case cooperative launch is unsupported.
// ===========================================================================
#define PACK_BLOCKS 784
#define XG_BLOCKS 400

__global__ __launch_bounds__(256) void k_prep(
    const int* __restrict__ idx, const float* __restrict__ emb,
    const float* __restrict__ Ws_w, const float* __restrict__ Ws_b,
    const float* __restrict__ mlp_w,
    unsigned short* __restrict__ Bp, unsigned short* __restrict__ x_ws,
    float* __restrict__ sumsq_ws, float* __restrict__ S_ws)
{
  __shared__ __align__(16) unsigned short smem[12800];
  const int bx = blockIdx.x;
  const int tid = threadIdx.x;

  if (bx < PACK_BLOCKS) {
    const size_t base_f = (size_t)bx * 64 * HID_DIM;
    const float4* src4 = (const float4*)(mlp_w + base_f);
    for (int i = tid; i < 3200; i += 256) {
      float4 f;
      if (base_f + 4 * (size_t)i + 4 <= (size_t)NUM_E * HID_DIM) f = src4[i];
      else f = make_float4(0.f, 0.f, 0.f, 0.f);
      unsigned short t4[4] __attribute__((aligned(8))) = {
        f2bf(f.x), f2bf(f.y), f2bf(f.z), f2bf(f.w)};
      *(uint2*)&smem[i * 4] = *(uint2*)t4;
    }
    __syncthreads();
    const int nt0 = bx * 4;
    unsigned short* dst = Bp + (size_t)nt0 * NKT * 512;
    for (int s = 0; s < 7; ++s) {
      const int fi = s * 256 + tid;
      const int fr = fi >> 6;
      const int ln = fi & 63;
      const int nt_l = fr / 7, kt = fr - nt_l * 7;
      const int r = nt_l * 16 + (ln & 15);
      const int kb = kt * 32 + (ln >> 4) * 8;
      uint4 val;
      if (kb < HID_DIM) val = *(const uint4*)&smem[r * HID_DIM + kb];
      else val = make_uint4(0, 0, 0, 0);
      *(uint4*)&dst[(size_t)fi * 8] = val;
    }
    return;
  }
  if (bx >= PACK_BLOCKS + XG_BLOCKS) {
    S_ws[tid] = 0.f;
    S_ws[256 + tid] = 0.f;
    return;
  }
  unsigned short* Al = smem;
  unsigned short* Bl = smem + 64 * 40;
  const int wave = tid >> 6, lane = tid & 63;
  const int q = lane >> 4, l15 = lane & 15;
  const int row0 = (bx - PACK_BLOCKS) * 64;

  f32x4 acc[13];
  for (int i = 0; i < 13; i++) acc[i] = (f32x4){0, 0, 0, 0};

  for (int kt = 0; kt < 4; ++kt) {
    const int k0 = kt * 32;
    {
      const int r = tid >> 2, q4 = tid & 3;
      const int erow = idx[row0 + r];
      const float* src = emb + (size_t)erow * EMBED_DIM + k0 + q4 * 8;
      float4 f0 = *(const float4*)(src);
      float4 f1 = *(const float4*)(src + 4);
      unsigned short tmp[8] __attribute__((aligned(16))) = {
        f2bf(f0.x), f2bf(f0.y), f2bf(f0.z), f2bf(f0.w),
        f2bf(f1.x), f2bf(f1.y), f2bf(f1.z), f2bf(f1.w)};
      *(uint4*)&Al[r * 40 + q4 * 8] = *(uint4*)tmp;
    }
    if (tid < 208) {
      unsigned short tmp[32] __attribute__((aligned(16)));
      if (tid < HID_DIM) {
        const float* src = Ws_w + (size_t)tid * EMBED_DIM + k0;
        for (int j = 0; j < 8; j++) {
          float4 f = *(const float4*)(src + j * 4);
          tmp[j*4+0] = f2bf(f.x); tmp[j*4+1] = f2bf(f.y);
          tmp[j*4+2] = f2bf(f.z); tmp[j*4+3] = f2bf(f.w);
        }
      } else {
        for (int j = 0; j < 32; j++) tmp[j] = 0;
      }
      for (int j = 0; j < 4; j++)
        *(uint4*)&Bl[tid * 40 + j * 8] = *(uint4*)&tmp[j * 8];
    }
    __syncthreads();
    s16x8 a = *(const s16x8*)&Al[(wave * 16 + l15) * 40 + q * 8];
    for (int ni = 0; ni < 13; ++ni) {
      s16x8 bfr = *(const s16x8*)&Bl[(ni * 16 + l15) * 40 + q * 8];
      acc[ni] = __builtin_amdgcn_mfma_f32_16x16x32_bf16(a, bfr, acc[ni], 0, 0, 0);
    }
    __syncthreads();
  }

  float sq[4] = {0, 0, 0, 0};
  for (int ni = 0; ni < 13; ++ni) {
    const int col = ni * 16 + l15;
    const bool cv = col < HID_DIM;
    const float bias = cv ? Ws_b[col] : 0.f;
    for (int p = 0; p < 4; p++) {
      float v = acc[ni][p] + bias;
      if (cv) sq[p] += v * v;
      const int grow = row0 + wave * 16 + q * 4 + p;
      x_ws[(size_t)grow * HPAD + col] = f2bf(cv ? v : 0.f);
    }
  }
  for (int m = 1; m < 16; m <<= 1)
    for (int p = 0; p < 4; p++) sq[p] += __shfl_xor(sq[p], m, 64);
  if (l15 == 0)
    for (int p = 0; p < 4; p++)
      sumsq_ws[row0 + wave * 16 + q * 4 + p] = sq[p];
}

__global__ __launch_bounds__(256) void k_routing(
    const int* __restrict__ idx, const int* __restrict__ times,
    const unsigned short* __restrict__ x_ws, const float* __restrict__ sumsq_ws,
    unsigned short* __restrict__ Ap, float* __restrict__ poses_f,
    float* __restrict__ expa_ws, float* __restrict__ D_ws)
{
  __shared__ float u[NN * 201];
  __shared__ float cc[NN];
  __shared__ float bb[NN];
  __shared__ float vv[HID_DIM];
  __shared__ float nrm[NN];
  __shared__ int   sidx[NN];
  __shared__ float red[4];
  __shared__ float scaleS;
  const int tid = threadIdx.x;
  const int b = blockIdx.x;

  if (tid < NN) {
    nrm[tid] = fmaxf(sqrtf(sumsq_ws[b * NN + tid]), 1e-12f);
    sidx[tid] = idx[b * NN + tid];
    bb[tid] = 2.0f / (1.0f + (float)times[b * NN + tid]);
  }
  __syncthreads();
  const int un = tid >> 2, uc0 = (tid & 3) * 50;
  if (un < NN) {
    const float inv = 1.0f / nrm[un];
    const unsigned short* xs = &x_ws[(size_t)(b * NN + un) * HPAD + uc0];
    for (int j = 0; j < 50; j++) u[un * 201 + uc0 + j] = bf2f(xs[j]) * inv;
  }
  __syncthreads();

  for (int it = 0; it < 3; ++it) {
    if (tid < 64) {
      float x = (tid < NN) ? bb[tid] : -1e30f;
      float m = x;
      for (int d = 1; d < 64; d <<= 1) m = fmaxf(m, __shfl_xor(m, d, 64));
      float e = (tid < NN) ? __expf(x - m) : 0.f;
      float s = e;
      for (int d = 1; d < 64; d <<= 1) s += __shfl_xor(s, d, 64);
      if (tid < NN) cc[tid] = e * (float)NN / s;
    }
    __syncthreads();
    float sh = 0.f;
    if (tid < HID_DIM)
      for (int n = 0; n < NN; n++) sh += cc[n] * u[n * 201 + tid];
    float sq = (tid < HID_DIM) ? sh * sh : 0.f;
    for (int d = 1; d < 64; d <<= 1) sq += __shfl_xor(sq, d, 64);
    if ((tid & 63) == 0) red[tid >> 6] = sq;
    __syncthreads();
    if (tid == 0) {
      const float t = red[0] + red[1] + red[2] + red[3];
      scaleS = t / (1.0f + t) / sqrtf(t + 1e-9f);
    }
    __syncthreads();
    if (tid < HID_DIM) vv[tid] = scaleS * sh;
    __syncthreads();
    if (it < 2) {
      float d = 0.f;
      if (un < NN)
        for (int j = 0; j < 50; j++) d += u[un * 201 + uc0 + j] * vv[uc0 + j];
      d += __shfl_xor(d, 1, 64);
      d += __shfl_xor(d, 2, 64);
      if (un < NN && (tid & 3) == 0) bb[un] += d;
      __syncthreads();
    }
  }
  if (tid < KPAD) {
    const float val = (tid < HID_DIM) ? vv[tid] : 0.f;
    const int kt = tid >> 5, rem = tid & 31, q = rem >> 3, j = rem & 7;
    const int mt = b >> 4, l15 = b & 15;
    Ap[(size_t)(((mt * NKT + kt) * 64) + q * 16 + l15) * 8 + j] = f2bf(val);
  }
  if (tid < HID_DIM) poses_f[b * HID_DIM + tid] = vv[tid];
  if (tid < 64) {
    float a = 0.f; int first = 1;
    const int my = (tid < NN) ? sidx[tid] : -1;
    if (tid < NN) {
      for (int n = 0; n < NN; n++)
        if (sidx[n] == my) { a += cc[n]; if (n < tid) first = 0; }
      expa_ws[b * NN + tid] = __expf(a);
    }
    float contrib = (tid < NN && first) ? (__expf(a) - 1.0f) : 0.f;
    for (int d = 1; d < 64; d <<= 1) contrib += __shfl_xor(contrib, d, 64);
    if (tid == 0) D_ws[b] = (float)NUM_E + contrib;
  }
}

template<int PASS>
__global__ __launch_bounds__(256, 4) void k_gemm(
    const unsigned short* __restrict__ Ap, const unsigned short* __restrict__ Bp,
    const float* __restrict__ mlp_b, const float* __restrict__ D_ws,
    float* __restrict__ S_ws, float* __restrict__ out)
{
  __shared__ __align__(16) char buf2[17920];
  const int id = blockIdx.x;
  const int yb = id / 200;
  const int xb = id - yb * 200;
  if (xb >= NXB) return;
  gemm_tile<PASS>(yb, xb, buf2, threadIdx.x, Ap, Bp, mlp_b, D_ws, S_ws, out);
}

__global__ __launch_bounds__(256) void k_fix(
    const int* __restrict__ idx, const float* __restrict__ expa,
    const float* __restrict__ poses_f, const float* __restrict__ mlp_w,
    const float* __restrict__ mlp_b, const float* __restrict__ D_ws,
    const float* __restrict__ S_ws, float* __restrict__ out)
{
  const int t = blockIdx.x * 4 + (threadIdx.x >> 6);
  const int lane = threadIdx.x & 63;
  if (t >= BATCH * NN) return;
  const int b = t / NN;
  const int j = idx[t];
  float dot = 0.f;
  for (int h = lane; h < HID_DIM; h += 64)
    dot += poses_f[b * HID_DIM + h] * mlp_w[(size_t)j * HID_DIM + h];
  for (int m = 1; m < 64; m <<= 1) dot += __shfl_xor(dot, m, 64);
  if (lane == 0) {
    const float s = dot + mlp_b[j];
    out[(size_t)b * NUM_E + j] = __logf(0.5f * expa[t] / D_ws[b] +
                                        0.5f * __expf(s) / S_ws[b]);
  }
}

extern "C" void kernel_launch(void* const* d_in, const int* in_sizes, int n_in,
                              void* d_out, int out_size, void* d_ws, size_t ws_size,
                              hipStream_t stream) {
  const int*   idx   = (const int*)d_in[0];
  const int*   times = (const int*)d_in[1];
  const float* emb   = (const float*)d_in[2];
  const float* Ws_w  = (const float*)d_in[3];
  const float* Ws_b  = (const float*)d_in[4];
  const float* mlp_w = (const float*)d_in[5];
  const float* mlp_b = (const float*)d_in[6];
  float* out = (float*)d_out;

  char* ws = (char*)d_ws;
  unsigned short* Bp    = (unsigned short*)ws; ws += (size_t)NTT2 * NKT * 64 * 8 * 2;  // 22.5 MB
  unsigned short* x_ws  = (unsigned short*)ws; ws += (size_t)BATCH * NN * HPAD * 2;    // 10.65 MB (fallback only)
  unsigned short* Ap    = (unsigned short*)ws; ws += (size_t)32 * NKT * 64 * 8 * 2;    // 229 KB
  float* poses_f        = (float*)ws;          ws += (size_t)BATCH * HID_DIM * 4;
  float* sumsq          = (float*)ws;          ws += (size_t)BATCH * NN * 4;           // fallback only
  float* expa           = (float*)ws;          ws += (size_t)BATCH * NN * 4;
  float* D_ws           = (float*)ws;          ws += (size_t)BATCH * 4;
  float* S_ws           = (float*)ws;          ws += (size_t)BATCH * 4;

  int nb = 0;
  hipError_t qerr = hipOccupancyMaxActiveBlocksPerMultiprocessor(&nb, k_all, 256, 0);
  if (qerr != hipSuccess || nb < 1) nb = 1;
  int g = nb * 256;
  if (g > MAXGRID) g = MAXGRID;

  void* args[] = {
    (void*)&idx, (void*)&times, (void*)&emb, (void*)&Ws_w, (void*)&Ws_b,
    (void*)&mlp_w, (void*)&mlp_b, (void*)&out, (void*)&Bp, (void*)&Ap,
    (void*)&poses_f, (void*)&expa, (void*)&D_ws, (void*)&S_ws};
  hipError_t err = hipLaunchCooperativeKernel(k_all, dim3(g), dim3(256), args, 0, stream);
  if (err == hipSuccess) return;

  // -------- fallback: proven r5 pipeline --------
  k_prep   <<<dim3(PACK_BLOCKS + XG_BLOCKS + 1), 256, 0, stream>>>(
      idx, emb, Ws_w, Ws_b, mlp_w, Bp, x_ws, sumsq, S_ws);
  k_routing<<<dim3(BATCH),        256, 0, stream>>>(idx, times, x_ws, sumsq, Ap, poses_f, expa, D_ws);
  k_gemm<0><<<dim3(1600),         256, 0, stream>>>(Ap, Bp, mlp_b, D_ws, S_ws, out);
  k_gemm<1><<<dim3(1600),         256, 0, stream>>>(Ap, Bp, mlp_b, D_ws, S_ws, out);
  k_fix    <<<dim3(BATCH * NN / 4), 256, 0, stream>>>(idx, expa, poses_f, mlp_w, mlp_b, D_ws, S_ws, out);
}

// Round 7
// 256.422 us; speedup vs baseline: 1.8495x; 1.8495x over previous
//
#include <hip/hip_runtime.h>
#include <stdint.h>

#define NUM_E 50000
#define EMBED_DIM 128
#define HID_DIM 200
#define BATCH 512
#define NN 50
#define KPAD 224
#define NKT 7      // K tiles of 32 for scores GEMM
#define NTT2 3136  // N fragment tiles padded: 3136*16 = 50176 = 196*256
#define NXB 196
#define PACK_UNITS 784
#define USTRIDE 201

typedef short s16x8 __attribute__((ext_vector_type(8)));
typedef float f32x4 __attribute__((ext_vector_type(4)));

__device__ inline unsigned short f2bf(float f) {
  union { float f; unsigned u; } v; v.f = f;
  unsigned r = v.u + 0x7FFF + ((v.u >> 16) & 1);
  return (unsigned short)(r >> 16);
}
__device__ inline float bf2f(unsigned short b) {
  union { unsigned u; float f; } v; v.u = ((unsigned)b) << 16;
  return v.f;
}

__device__ __forceinline__ void gl_lds16(const unsigned short* g, unsigned short* l) {
  __builtin_amdgcn_global_load_lds(
      (const __attribute__((address_space(1))) unsigned int*)g,
      (__attribute__((address_space(3))) unsigned int*)l, 16, 0, 0);
}

// ---------------------------------------------------------------------------
// scores-GEMM tile (64M x 256N, K=224).
// buf: [0,16384) = Bs staging; [16384,17408) = red (invD/invS or partials).
// ---------------------------------------------------------------------------
template<int PASS>
__device__ __forceinline__ void gemm_tile(
    int yb, int xb, char* buf, int tid,
    const unsigned short* Ap, const unsigned short* Bp, const float* mlp_b,
    const float* D_ws, float* S_ws, float* out)
{
  unsigned short* Bs = (unsigned short*)buf;
  float* red = (float*)(buf + 16384);
  const int w = tid >> 6, lane = tid & 63;
  const int q = lane >> 4, l15 = lane & 15;
  const int mt0 = yb * 4;
  const int m0 = yb * 64;
  const int ntb = xb * 16 + w * 4;

  if (PASS == 1 && tid < 64) {
    red[tid]      = 0.5f / D_ws[m0 + tid];
    red[64 + tid] = 0.5f / S_ws[m0 + tid];
  }
  float bias[4];
  #pragma unroll
  for (int nl = 0; nl < 4; ++nl) {
    const int col = (ntb + nl) * 16 + l15;
    bias[nl] = (col < NUM_E) ? mlp_b[col] : 0.f;
  }
  const unsigned short* apBase = Ap + (size_t)mt0 * NKT * 512;

  f32x4 acc[4][4];
  #pragma unroll
  for (int i = 0; i < 4; i++)
    #pragma unroll
    for (int j = 0; j < 4; j++) acc[i][j] = (f32x4){0, 0, 0, 0};

  for (int kt = 0; kt < NKT; ++kt) {
    #pragma unroll
    for (int nl = 0; nl < 4; ++nl)
      gl_lds16(Bp + ((size_t)(ntb + nl) * NKT + kt) * 512 + lane * 8,
               &Bs[(w * 4 + nl) * 512]);
    s16x8 a[4];
    #pragma unroll
    for (int mi = 0; mi < 4; ++mi)
      a[mi] = *(const s16x8*)&apBase[((mi * NKT + kt) * 64 + lane) * 8];
    __syncthreads();
    s16x8 bfr[4];
    #pragma unroll
    for (int nl = 0; nl < 4; ++nl)
      bfr[nl] = *(const s16x8*)&Bs[((w * 4 + nl) * 64 + lane) * 8];
    #pragma unroll
    for (int nl = 0; nl < 4; ++nl)
      #pragma unroll
      for (int mi = 0; mi < 4; ++mi)
        acc[mi][nl] = __builtin_amdgcn_mfma_f32_16x16x32_bf16(a[mi], bfr[nl], acc[mi][nl], 0, 0, 0);
    __syncthreads();
  }

  if (PASS == 0) {
    float rs[4][4];
    #pragma unroll
    for (int mi = 0; mi < 4; mi++)
      #pragma unroll
      for (int p = 0; p < 4; p++) rs[mi][p] = 0.f;
    #pragma unroll
    for (int mi = 0; mi < 4; ++mi)
      #pragma unroll
      for (int nl = 0; nl < 4; ++nl) {
        const int col = (ntb + nl) * 16 + l15;
        #pragma unroll
        for (int p = 0; p < 4; p++) {
          const float v = acc[mi][nl][p] + bias[nl];
          rs[mi][p] += (col < NUM_E) ? __expf(v) : 0.f;
        }
      }
    #pragma unroll
    for (int m = 1; m < 16; m <<= 1)
      for (int mi = 0; mi < 4; mi++)
        for (int p = 0; p < 4; p++)
          rs[mi][p] += __shfl_xor(rs[mi][p], m, 64);
    if (l15 == 0)
      for (int mi = 0; mi < 4; mi++)
        for (int p = 0; p < 4; p++)
          red[w * 64 + mi * 16 + q * 4 + p] = rs[mi][p];
    __syncthreads();
    if (tid < 64)
      atomicAdd(&S_ws[m0 + tid],
                red[tid] + red[64 + tid] + red[128 + tid] + red[192 + tid]);
  } else {
    #pragma unroll
    for (int mi = 0; mi < 4; ++mi) {
      #pragma unroll
      for (int p = 0; p < 4; p++) {
        const int rl = mi * 16 + q * 4 + p;
        const float invD = red[rl];
        const float invS = red[64 + rl];
        const int row = m0 + rl;
        #pragma unroll
        for (int nl = 0; nl < 4; ++nl) {
          const int col = (ntb + nl) * 16 + l15;
          if (col < NUM_E) {
            const float v = acc[mi][nl][p] + bias[nl];
            out[(size_t)row * NUM_E + col] = __logf(fmaf(__expf(v), invS, invD));
          }
        }
      }
    }
  }
}

// ---------------------------------------------------------------------------
// Stage 1: grid = 512 batch blocks (fused xgemm+routing, one block per batch
// row) + 784 pack blocks (mlp_w -> Bp fragments) + 1 S-zero block.
// ---------------------------------------------------------------------------
__global__ __launch_bounds__(256, 3) void k_stage1(
    const int* __restrict__ idx, const int* __restrict__ times,
    const float* __restrict__ emb, const float* __restrict__ Ws_w,
    const float* __restrict__ Ws_b, const float* __restrict__ mlp_w,
    unsigned short* __restrict__ Bp, unsigned short* __restrict__ Ap,
    float* __restrict__ poses_f, float* __restrict__ expa_ws,
    float* __restrict__ D_ws, float* __restrict__ S_ws)
{
  __shared__ __align__(16) char buf[40320];
  __shared__ float cc[NN], bb[NN], vv[HID_DIM], red4[4], scaleS;
  __shared__ int sidx[NN];
  const int u = blockIdx.x;
  const int tid = threadIdx.x;
  const int w = tid >> 6, lane = tid & 63;
  const int q = lane >> 4, l15 = lane & 15;

  if (u < BATCH) {
    // ================= fused xgemm + routing for batch row u ==============
    const int b = u;
    if (tid < NN) {
      sidx[tid] = idx[b * NN + tid];
      bb[tid] = 2.0f / (1.0f + (float)times[b * NN + tid]);
    }
    __syncthreads();
    unsigned short* Afr = (unsigned short*)buf;            // 16384 B
    unsigned short* Bfr = (unsigned short*)(buf + 16384);  // 13312 B per kt
    // stage A fragments: 64 rows (>=NN zero) x 128 k, gather from emb
    for (int v = tid; v < 1024; v += 256) {
      const int row = v >> 4, c = v & 15;
      const int kt = c >> 2, qq = c & 3;
      unsigned short tmp[8] __attribute__((aligned(16)));
      if (row < NN) {
        const float* src = emb + (size_t)sidx[row] * EMBED_DIM + c * 8;
        float4 f0 = *(const float4*)src;
        float4 f1 = *(const float4*)(src + 4);
        tmp[0] = f2bf(f0.x); tmp[1] = f2bf(f0.y); tmp[2] = f2bf(f0.z); tmp[3] = f2bf(f0.w);
        tmp[4] = f2bf(f1.x); tmp[5] = f2bf(f1.y); tmp[6] = f2bf(f1.z); tmp[7] = f2bf(f1.w);
      } else {
        for (int j = 0; j < 8; j++) tmp[j] = 0;
      }
      *(uint4*)&Afr[(((row >> 4) * 4 + kt) * 64 + qq * 16 + (row & 15)) * 8] = *(uint4*)tmp;
    }
    f32x4 acc[4][4];
    #pragma unroll
    for (int i = 0; i < 4; i++)
      #pragma unroll
      for (int j = 0; j < 4; j++) acc[i][j] = (f32x4){0, 0, 0, 0};
    __syncthreads();
    for (int kt = 0; kt < 4; ++kt) {
      // stage B kt-slice: 208 n (>=HID zero) x 32 k from Ws_w
      for (int v = tid; v < 832; v += 256) {
        const int n = v >> 2, cq = v & 3;
        unsigned short tmp[8] __attribute__((aligned(16)));
        if (n < HID_DIM) {
          const float* src = Ws_w + (size_t)n * EMBED_DIM + kt * 32 + cq * 8;
          float4 f0 = *(const float4*)src;
          float4 f1 = *(const float4*)(src + 4);
          tmp[0] = f2bf(f0.x); tmp[1] = f2bf(f0.y); tmp[2] = f2bf(f0.z); tmp[3] = f2bf(f0.w);
          tmp[4] = f2bf(f1.x); tmp[5] = f2bf(f1.y); tmp[6] = f2bf(f1.z); tmp[7] = f2bf(f1.w);
        } else {
          for (int j = 0; j < 8; j++) tmp[j] = 0;
        }
        *(uint4*)&Bfr[((n >> 4) * 64 + cq * 16 + (n & 15)) * 8] = *(uint4*)tmp;
      }
      __syncthreads();
      s16x8 a[4];
      #pragma unroll
      for (int mt = 0; mt < 4; ++mt)
        a[mt] = *(const s16x8*)&Afr[((mt * 4 + kt) * 64 + lane) * 8];
      #pragma unroll
      for (int ii = 0; ii < 4; ++ii) {
        const int nt = w + ii * 4;
        if (nt < 13) {
          s16x8 bv = *(const s16x8*)&Bfr[(nt * 64 + lane) * 8];
          #pragma unroll
          for (int mt = 0; mt < 4; ++mt)
            acc[mt][ii] = __builtin_amdgcn_mfma_f32_16x16x32_bf16(a[mt], bv, acc[mt][ii], 0, 0, 0);
        }
      }
      __syncthreads();
    }
    // epilogue: x = acc + Ws_b into u-matrix (fp32, overlays frag LDS)
    float* uu = (float*)buf;
    #pragma unroll
    for (int ii = 0; ii < 4; ++ii) {
      const int nt = w + ii * 4;
      if (nt < 13) {
        const int col = nt * 16 + l15;
        if (col < HID_DIM) {
          const float bv = Ws_b[col];
          #pragma unroll
          for (int mt = 0; mt < 4; ++mt)
            #pragma unroll
            for (int p = 0; p < 4; p++) {
              const int row = mt * 16 + q * 4 + p;
              if (row < NN) uu[row * USTRIDE + col] = acc[mt][ii][p] + bv;
            }
        }
      }
    }
    __syncthreads();
    // L2-normalize rows (4 threads/row)
    const int un = tid >> 2, uc0 = (tid & 3) * 50;
    if (un < NN) {
      float s = 0.f;
      for (int j = 0; j < 50; j++) {
        const float x = uu[un * USTRIDE + uc0 + j];
        s += x * x;
      }
      s += __shfl_xor(s, 1, 64);
      s += __shfl_xor(s, 2, 64);
      const float inv = 1.0f / fmaxf(sqrtf(s), 1e-12f);
      for (int j = 0; j < 50; j++) uu[un * USTRIDE + uc0 + j] *= inv;
    }
    __syncthreads();
    // dynamic routing, 3 iters
    for (int it = 0; it < 3; ++it) {
      if (tid < 64) {
        float x = (tid < NN) ? bb[tid] : -1e30f;
        float m = x;
        for (int d = 1; d < 64; d <<= 1) m = fmaxf(m, __shfl_xor(m, d, 64));
        float e = (tid < NN) ? __expf(x - m) : 0.f;
        float s = e;
        for (int d = 1; d < 64; d <<= 1) s += __shfl_xor(s, d, 64);
        if (tid < NN) cc[tid] = e * (float)NN / s;
      }
      __syncthreads();
      float sh = 0.f;
      if (tid < HID_DIM)
        for (int n = 0; n < NN; n++) sh += cc[n] * uu[n * USTRIDE + tid];
      float sq2 = (tid < HID_DIM) ? sh * sh : 0.f;
      for (int d = 1; d < 64; d <<= 1) sq2 += __shfl_xor(sq2, d, 64);
      if ((tid & 63) == 0) red4[tid >> 6] = sq2;
      __syncthreads();
      if (tid == 0) {
        const float t2 = red4[0] + red4[1] + red4[2] + red4[3];
        scaleS = t2 / (1.0f + t2) / sqrtf(t2 + 1e-9f);
      }
      __syncthreads();
      if (tid < HID_DIM) vv[tid] = scaleS * sh;
      __syncthreads();
      if (it < 2) {
        float d = 0.f;
        if (un < NN)
          for (int j = 0; j < 50; j++)
            d += uu[un * USTRIDE + uc0 + j] * vv[uc0 + j];
        d += __shfl_xor(d, 1, 64);
        d += __shfl_xor(d, 2, 64);
        if (un < NN && (tid & 3) == 0) bb[un] += d;
        __syncthreads();
      }
    }
    // outputs: Ap fragments, fp32 poses, expa, D_b
    if (tid < KPAD) {
      const float val = (tid < HID_DIM) ? vv[tid] : 0.f;
      const int kt = tid >> 5, rem = tid & 31, qq = rem >> 3, j = rem & 7;
      const int mt = b >> 4, ll = b & 15;
      Ap[(size_t)(((mt * NKT + kt) * 64) + qq * 16 + ll) * 8 + j] = f2bf(val);
    }
    if (tid < HID_DIM) poses_f[b * HID_DIM + tid] = vv[tid];
    if (tid < 64) {
      float a2 = 0.f; int first = 1;
      const int my = (tid < NN) ? sidx[tid] : -1;
      if (tid < NN) {
        for (int n = 0; n < NN; n++)
          if (sidx[n] == my) { a2 += cc[n]; if (n < tid) first = 0; }
        expa_ws[b * NN + tid] = __expf(a2);
      }
      float contrib = (tid < NN && first) ? (__expf(a2) - 1.0f) : 0.f;
      for (int d = 1; d < 64; d <<= 1) contrib += __shfl_xor(contrib, d, 64);
      if (tid == 0) D_ws[b] = (float)NUM_E + contrib;
    }
  } else if (u < BATCH + PACK_UNITS) {
    // ================= coalesced pack of 4 n-tiles into Bp =================
    const int pb = u - BATCH;
    unsigned short* smem = (unsigned short*)buf;
    const size_t base_f = (size_t)pb * 64 * HID_DIM;
    const float4* src4 = (const float4*)(mlp_w + base_f);
    for (int i = tid; i < 3200; i += 256) {
      float4 f;
      if (base_f + 4 * (size_t)i + 4 <= (size_t)NUM_E * HID_DIM) f = src4[i];
      else f = make_float4(0.f, 0.f, 0.f, 0.f);
      unsigned short t4[4] __attribute__((aligned(8))) = {
        f2bf(f.x), f2bf(f.y), f2bf(f.z), f2bf(f.w)};
      *(uint2*)&smem[i * 4] = *(uint2*)t4;
    }
    __syncthreads();
    const int nt0 = pb * 4;
    unsigned short* dst = Bp + (size_t)nt0 * NKT * 512;
    for (int s2 = 0; s2 < 7; ++s2) {
      const int fi = s2 * 256 + tid;
      const int fr = fi >> 6;
      const int ln = fi & 63;
      const int nt_l = fr / 7, kt = fr - nt_l * 7;
      const int r = nt_l * 16 + (ln & 15);
      const int kb = kt * 32 + (ln >> 4) * 8;
      uint4 val;
      if (kb < HID_DIM) val = *(const uint4*)&smem[r * HID_DIM + kb];
      else val = make_uint4(0, 0, 0, 0);
      *(uint4*)&dst[(size_t)fi * 8] = val;
    }
  } else {
    S_ws[tid] = 0.f;
    S_ws[256 + tid] = 0.f;
  }
}

// ---------------------------------------------------------------------------
// Kernel G: XCD-swizzled 1-D grid of 1600: xb = id % 200 (skip >= 196),
// yb = id / 200. Stride 200 == 0 mod 8 keeps a Bp column-slice on one XCD.
// ---------------------------------------------------------------------------
template<int PASS>
__global__ __launch_bounds__(256, 4) void k_gemm(
    const unsigned short* __restrict__ Ap, const unsigned short* __restrict__ Bp,
    const float* __restrict__ mlp_b, const float* __restrict__ D_ws,
    float* __restrict__ S_ws, float* __restrict__ out)
{
  __shared__ __align__(16) char buf2[17408];
  const int id = blockIdx.x;
  const int yb = id / 200;
  const int xb = id - yb * 200;
  if (xb >= NXB) return;
  gemm_tile<PASS>(yb, xb, buf2, threadIdx.x, Ap, Bp, mlp_b, D_ws, S_ws, out);
}

// ---------------------------------------------------------------------------
// Kernel D: fixup history positions; recompute score via fp32 dot product.
// ---------------------------------------------------------------------------
__global__ __launch_bounds__(256) void k_fix(
    const int* __restrict__ idx, const float* __restrict__ expa,
    const float* __restrict__ poses_f, const float* __restrict__ mlp_w,
    const float* __restrict__ mlp_b, const float* __restrict__ D_ws,
    const float* __restrict__ S_ws, float* __restrict__ out)
{
  const int t = blockIdx.x * 4 + (threadIdx.x >> 6);
  const int lane = threadIdx.x & 63;
  if (t >= BATCH * NN) return;
  const int b = t / NN;
  const int j = idx[t];
  float dot = 0.f;
  for (int h = lane; h < HID_DIM; h += 64)
    dot += poses_f[b * HID_DIM + h] * mlp_w[(size_t)j * HID_DIM + h];
  for (int m = 1; m < 64; m <<= 1) dot += __shfl_xor(dot, m, 64);
  if (lane == 0) {
    const float s = dot + mlp_b[j];
    out[(size_t)b * NUM_E + j] = __logf(0.5f * expa[t] / D_ws[b] +
                                        0.5f * __expf(s) / S_ws[b]);
  }
}

extern "C" void kernel_launch(void* const* d_in, const int* in_sizes, int n_in,
                              void* d_out, int out_size, void* d_ws, size_t ws_size,
                              hipStream_t stream) {
  const int*   idx   = (const int*)d_in[0];
  const int*   times = (const int*)d_in[1];
  const float* emb   = (const float*)d_in[2];
  const float* Ws_w  = (const float*)d_in[3];
  const float* Ws_b  = (const float*)d_in[4];
  const float* mlp_w = (const float*)d_in[5];
  const float* mlp_b = (const float*)d_in[6];
  float* out = (float*)d_out;

  char* ws = (char*)d_ws;
  unsigned short* Bp    = (unsigned short*)ws; ws += (size_t)NTT2 * NKT * 64 * 8 * 2;  // 22.5 MB
  unsigned short* Ap    = (unsigned short*)ws; ws += (size_t)32 * NKT * 64 * 8 * 2;    // 229 KB
  float* poses_f        = (float*)ws;          ws += (size_t)BATCH * HID_DIM * 4;      // 410 KB
  float* expa           = (float*)ws;          ws += (size_t)BATCH * NN * 4;           // 102 KB
  float* D_ws           = (float*)ws;          ws += (size_t)BATCH * 4;
  float* S_ws           = (float*)ws;          ws += (size_t)BATCH * 4;

  k_stage1 <<<dim3(BATCH + PACK_UNITS + 1), 256, 0, stream>>>(
      idx, times, emb, Ws_w, Ws_b, mlp_w, Bp, Ap, poses_f, expa, D_ws, S_ws);
  k_gemm<0><<<dim3(1600),           256, 0, stream>>>(Ap, Bp, mlp_b, D_ws, S_ws, out);
  k_gemm<1><<<dim3(1600),           256, 0, stream>>>(Ap, Bp, mlp_b, D_ws, S_ws, out);
  k_fix    <<<dim3(BATCH * NN / 4), 256, 0, stream>>>(idx, expa, poses_f, mlp_w, mlp_b, D_ws, S_ws, out);
}